// Round 4
// baseline (472.814 us; speedup 1.0000x reference)
//
#include <hip/hip_runtime.h>
#include <math.h>

// B=4, S=2048, E=1024, H=16, D=64
constexpr int Bn = 4;
constexpr int Sn = 2048;
constexpr int En = 1024;
constexpr int Hn = 16;
constexpr int Dn = 64;

typedef float f32x4 __attribute__((ext_vector_type(4)));
typedef short s16x8 __attribute__((ext_vector_type(8)));
typedef short s16x4 __attribute__((ext_vector_type(4)));

__device__ __forceinline__ short f2bf(float f) {
    unsigned u = __builtin_bit_cast(unsigned, f);
    unsigned r = (u + 0x7fffu + ((u >> 16) & 1u)) >> 16;
    return (short)r;
}

// async global->LDS, 16B per lane; LDS dest = wave-uniform base + lane*16
__device__ __forceinline__ void glds16(const short* g, short* l) {
    __builtin_amdgcn_global_load_lds(
        (const __attribute__((address_space(1))) short*)g,
        (__attribute__((address_space(3))) short*)l, 16, 0, 0);
}

// ---------------------------------------------------------------------------
// Conversion kernels
// ---------------------------------------------------------------------------
__global__ __launch_bounds__(256) void conv_x_kernel(
    const float* __restrict__ x, short* __restrict__ y)
{
    size_t i = ((size_t)blockIdx.x * 256 + threadIdx.x) * 4;
    float4 v = *(const float4*)(x + i);
    s16x4 o;
    o[0] = f2bf(v.x); o[1] = f2bf(v.y); o[2] = f2bf(v.z); o[3] = f2bf(v.w);
    *(s16x4*)(y + i) = o;
}

// Build Wcat[n][k] bf16 (n = p*1024 + h*64 + d, k = e) and bias_cat[n].
__global__ __launch_bounds__(256) void build_wcat_kernel(
    const float* __restrict__ Wq, const float* __restrict__ bq,
    const float* __restrict__ Wk, const float* __restrict__ bk,
    const float* __restrict__ Wv, const float* __restrict__ bv,
    short* __restrict__ Wcat, float* __restrict__ bias_cat)
{
    const int n = blockIdx.x;            // 0..3071
    const int p = n >> 10;
    const int h = (n >> 6) & 15;
    const int d = n & 63;
    const float* W = (p == 0) ? Wq : (p == 1) ? Wk : Wv;
    const float* bb = (p == 0) ? bq : (p == 1) ? bk : bv;
    const float* Wh = W + (size_t)h * En * Dn;
    short* dst = Wcat + (size_t)n * En;
    #pragma unroll
    for (int i = 0; i < 4; i++) {
        int k = threadIdx.x + i * 256;
        dst[k] = f2bf(Wh[(size_t)k * Dn + d]);
    }
    if (threadIdx.x == 0) bias_cat[n] = bb[h * Dn + d];
}

__global__ __launch_bounds__(256) void conv_wo_kernel(
    const float* __restrict__ Wo, short* __restrict__ Wob)
{
    const size_t base = (size_t)blockIdx.x * En;
    #pragma unroll
    for (int i = 0; i < 4; i++) {
        int k = threadIdx.x + i * 256;
        Wob[base + k] = f2bf(Wo[base + k]);
    }
}

// ---------------------------------------------------------------------------
// bf16 MFMA GEMM: C[M x N] = A[M x 1024] @ Bt[N x 1024]^T (+ bias)
// 128x128 tile, BK=64, global_load_lds staging, XOR-swizzled LDS.
// LDS layout: tile row = 8 chunks of 8 shorts; physical chunk p holds logical
// k-part (p&7)^(row&7). Fragment reads then hit banks 2-way (free, m136).
// ---------------------------------------------------------------------------
__global__ __launch_bounds__(256) void gemm_bt_kernel(
    const short* __restrict__ A,   // [M][1024] bf16
    const short* __restrict__ Bt,  // [N][1024] bf16
    const float* __restrict__ bias,
    float* __restrict__ outF,
    short* __restrict__ Qb, short* __restrict__ Kb, short* __restrict__ Vtb,
    int mode)
{
    constexpr int K = En;
    const int m0 = blockIdx.x * 128;
    const int n0 = blockIdx.y * 128;

    __shared__ short As[128 * 64];
    __shared__ short Bs[128 * 64];

    const int tid  = threadIdx.x;
    const int w    = tid >> 6;
    const int lane = tid & 63;
    const int quad = lane >> 4;
    const int l15  = lane & 15;
    const int wr = (w >> 1) * 64;
    const int wc = (w & 1) * 64;

    f32x4 acc[4][4];
    #pragma unroll
    for (int i = 0; i < 4; i++)
        #pragma unroll
        for (int j = 0; j < 4; j++)
            #pragma unroll
            for (int e = 0; e < 4; e++) acc[i][j][e] = 0.f;

    for (int k0 = 0; k0 < K; k0 += 64) {
        // stage A,B: 128 rows x 64 shorts each = 1024 chunks of 16B per tile
        #pragma unroll
        for (int r = 0; r < 4; r++) {
            int c   = (r * 4 + w) * 64 + lane;
            int row = c >> 3;
            int lp  = (c & 7) ^ (row & 7);
            glds16(A + (size_t)(m0 + row) * K + k0 + lp * 8,
                   As + (r * 4 + w) * 512);
            glds16(Bt + (size_t)(n0 + row) * K + k0 + lp * 8,
                   Bs + (r * 4 + w) * 512);
        }
        __syncthreads();

        #pragma unroll
        for (int ks = 0; ks < 2; ks++) {
            s16x8 af[4], bfr[4];
            #pragma unroll
            for (int mt = 0; mt < 4; mt++) {
                int row = wr + mt * 16 + l15;
                af[mt] = *(const s16x8*)&As[row * 64 + (((ks * 4 + quad) ^ (l15 & 7)) * 8)];
            }
            #pragma unroll
            for (int nt = 0; nt < 4; nt++) {
                int row = wc + nt * 16 + l15;
                bfr[nt] = *(const s16x8*)&Bs[row * 64 + (((ks * 4 + quad) ^ (l15 & 7)) * 8)];
            }
            #pragma unroll
            for (int mt = 0; mt < 4; mt++)
                #pragma unroll
                for (int nt = 0; nt < 4; nt++)
                    acc[mt][nt] = __builtin_amdgcn_mfma_f32_16x16x32_bf16(
                        af[mt], bfr[nt], acc[mt][nt], 0, 0, 0);
        }
        __syncthreads();
    }

    // epilogue
    if (mode == 0) {
        #pragma unroll
        for (int mt = 0; mt < 4; mt++) {
            #pragma unroll
            for (int reg = 0; reg < 4; reg++) {
                int m = m0 + wr + mt * 16 + quad * 4 + reg;
                #pragma unroll
                for (int nt = 0; nt < 4; nt++) {
                    int n = n0 + wc + nt * 16 + l15;
                    outF[(size_t)m * En + n] = acc[mt][nt][reg] + bias[n];
                }
            }
        }
    } else {
        const int p = (n0 + wc) >> 10;   // uniform over 64-wide wave tile
        #pragma unroll
        for (int mt = 0; mt < 4; mt++) {
            #pragma unroll
            for (int reg = 0; reg < 4; reg++) {
                int m = m0 + wr + mt * 16 + quad * 4 + reg;
                int b = m >> 11, s = m & 2047;
                #pragma unroll
                for (int nt = 0; nt < 4; nt++) {
                    int n = n0 + wc + nt * 16 + l15;
                    int h = (n >> 6) & 15, d = n & 63;
                    short v = f2bf(acc[mt][nt][reg] + bias[n]);
                    if (p == 0)
                        Qb[(((size_t)(b * Hn + h)) * Sn + s) * Dn + d] = v;
                    else if (p == 1)
                        Kb[(((size_t)(b * Hn + h)) * Sn + s) * Dn + d] = v;
                    else
                        Vtb[(((size_t)(b * Hn + h)) * Dn + d) * Sn + s] = v;
                }
            }
        }
    }
}

// ---------------------------------------------------------------------------
// Flash attention, bf16 MFMA. 128 q-rows per block (2 frags of 64), KV tile 64.
// K/V staged via global_load_lds with XOR swizzle. Blocks launched big-qt-first.
// ---------------------------------------------------------------------------
__global__ __launch_bounds__(256) void attn_mfma_kernel(
    const short* __restrict__ Q, const short* __restrict__ K,
    const short* __restrict__ Vt, short* __restrict__ Cb)
{
    constexpr int PP = 72;   // Ps pitch in shorts (padded; VALU-written)
    const int qt = (gridDim.x - 1) - blockIdx.x;  // 0..15, reversed for tail
    const int bh = blockIdx.y;                    // 0..63
    const int b = bh >> 4, h = bh & 15;

    __shared__ short Ks[64 * 64];    // [kv][d], swizzled
    __shared__ short Vts[64 * 64];   // [d][kv], swizzled
    __shared__ short Ps[128 * PP];

    const int tid  = threadIdx.x;
    const int w    = tid >> 6;
    const int lane = tid & 63;
    const int quad = lane >> 4;
    const int l15  = lane & 15;

    const short* Qp = Q + ((size_t)bh * Sn + qt * 128) * Dn;
    const short* Kp = K + (size_t)bh * Sn * Dn;
    const short* Vp = Vt + (size_t)bh * Dn * Sn;

    // Q fragments: frag f covers q rows qt*128 + f*64 + [0,64)
    s16x8 aq[2][2];
    #pragma unroll
    for (int f = 0; f < 2; f++)
        #pragma unroll
        for (int ks = 0; ks < 2; ks++)
            aq[f][ks] = *(const s16x8*)(
                Qp + (size_t)(f * 64 + w * 16 + l15) * Dn + ks * 32 + quad * 8);

    f32x4 acc[2][4];
    float mrow[2][4], lrow[2][4];
    #pragma unroll
    for (int f = 0; f < 2; f++)
        #pragma unroll
        for (int nt = 0; nt < 4; nt++)
            #pragma unroll
            for (int e = 0; e < 4; e++) acc[f][nt][e] = 0.f;
    #pragma unroll
    for (int f = 0; f < 2; f++)
        #pragma unroll
        for (int r = 0; r < 4; r++) { mrow[f][r] = -1e30f; lrow[f][r] = 0.f; }

    const float scale = 0.125f;

    for (int kt = 0; kt <= 2 * qt + 1; kt++) {
        // stage K tile [64 kv][64 d] and Vt tile [64 d][64 kv], swizzled
        #pragma unroll
        for (int r = 0; r < 2; r++) {
            int c   = (r * 4 + w) * 64 + lane;
            int row = c >> 3;
            int lp  = (c & 7) ^ (row & 7);
            glds16(Kp + (size_t)(kt * 64 + row) * Dn + lp * 8,
                   Ks + (r * 4 + w) * 512);
            glds16(Vp + (size_t)row * Sn + kt * 64 + lp * 8,
                   Vts + (r * 4 + w) * 512);
        }
        __syncthreads();

        // QK^T
        f32x4 sacc[2][4];
        #pragma unroll
        for (int f = 0; f < 2; f++)
            #pragma unroll
            for (int nt = 0; nt < 4; nt++)
                #pragma unroll
                for (int e = 0; e < 4; e++) sacc[f][nt][e] = 0.f;
        #pragma unroll
        for (int ks = 0; ks < 2; ks++) {
            s16x8 bk[4];
            #pragma unroll
            for (int nt = 0; nt < 4; nt++)
                bk[nt] = *(const s16x8*)&Ks[(nt * 16 + l15) * 64 +
                                            (((ks * 4 + quad) ^ (l15 & 7)) * 8)];
            #pragma unroll
            for (int f = 0; f < 2; f++) {
                if (kt > 2 * qt + f) continue;   // frag fully masked
                #pragma unroll
                for (int nt = 0; nt < 4; nt++)
                    sacc[f][nt] = __builtin_amdgcn_mfma_f32_16x16x32_bf16(
                        aq[f][ks], bk[nt], sacc[f][nt], 0, 0, 0);
            }
        }

        // scale + mask + online softmax (row = quad*4+reg, 16-lane reduce)
        #pragma unroll
        for (int f = 0; f < 2; f++) {
            if (kt > 2 * qt + f) continue;
            const bool diag = (kt == 2 * qt + f);
            const int qrow0 = qt * 128 + f * 64 + w * 16 + quad * 4;
            float alpha[4];
            #pragma unroll
            for (int reg = 0; reg < 4; reg++) {
                float sv[4];
                #pragma unroll
                for (int nt = 0; nt < 4; nt++) {
                    float v = sacc[f][nt][reg] * scale;
                    if (diag && (kt * 64 + nt * 16 + l15) > (qrow0 + reg))
                        v = -1e30f;
                    sv[nt] = v;
                }
                float rmax = fmaxf(fmaxf(sv[0], sv[1]), fmaxf(sv[2], sv[3]));
                #pragma unroll
                for (int off = 1; off < 16; off <<= 1)
                    rmax = fmaxf(rmax, __shfl_xor(rmax, off));
                float mnew = fmaxf(mrow[f][reg], rmax);
                alpha[reg] = __expf(mrow[f][reg] - mnew);
                mrow[f][reg] = mnew;
                float rs = 0.f;
                #pragma unroll
                for (int nt = 0; nt < 4; nt++) {
                    float pv = __expf(sv[nt] - mnew);
                    Ps[(f * 64 + w * 16 + quad * 4 + reg) * PP + nt * 16 + l15] =
                        f2bf(pv);
                    rs += pv;
                }
                #pragma unroll
                for (int off = 1; off < 16; off <<= 1)
                    rs += __shfl_xor(rs, off);
                lrow[f][reg] = lrow[f][reg] * alpha[reg] + rs;
            }
            #pragma unroll
            for (int nt = 0; nt < 4; nt++)
                #pragma unroll
                for (int reg = 0; reg < 4; reg++)
                    acc[f][nt][reg] *= alpha[reg];
        }

        // PV: O += P @ V   (Ps written/read by same wave's rows; lgkmcnt only)
        #pragma unroll
        for (int ks = 0; ks < 2; ks++) {
            s16x8 bv[4];
            #pragma unroll
            for (int nt = 0; nt < 4; nt++)
                bv[nt] = *(const s16x8*)&Vts[(nt * 16 + l15) * 64 +
                                             (((ks * 4 + quad) ^ (l15 & 7)) * 8)];
            #pragma unroll
            for (int f = 0; f < 2; f++) {
                if (kt > 2 * qt + f) continue;
                s16x8 ap = *(const s16x8*)&Ps[(f * 64 + w * 16 + l15) * PP +
                                              ks * 32 + quad * 8];
                #pragma unroll
                for (int nt = 0; nt < 4; nt++)
                    acc[f][nt] = __builtin_amdgcn_mfma_f32_16x16x32_bf16(
                        ap, bv[nt], acc[f][nt], 0, 0, 0);
            }
        }
        __syncthreads();
    }

    // epilogue: conc[b][s][h*64+d] bf16
    #pragma unroll
    for (int f = 0; f < 2; f++) {
        #pragma unroll
        for (int reg = 0; reg < 4; reg++) {
            int s = qt * 128 + f * 64 + w * 16 + quad * 4 + reg;
            float inv = 1.f / lrow[f][reg];
            #pragma unroll
            for (int nt = 0; nt < 4; nt++) {
                int d = nt * 16 + l15;
                Cb[((size_t)(b * Sn + s)) * En + h * Dn + d] =
                    f2bf(acc[f][nt][reg] * inv);
            }
        }
    }
}

// ---------------------------------------------------------------------------
extern "C" void kernel_launch(void* const* d_in, const int* in_sizes, int n_in,
                              void* d_out, int out_size, void* d_ws, size_t ws_size,
                              hipStream_t stream) {
    const float* x  = (const float*)d_in[0];
    const float* Wq = (const float*)d_in[1];
    const float* bq = (const float*)d_in[2];
    const float* Wk = (const float*)d_in[3];
    const float* bk = (const float*)d_in[4];
    const float* Wv = (const float*)d_in[5];
    const float* bv = (const float*)d_in[6];
    const float* Wo = (const float*)d_in[7];
    const float* bo = (const float*)d_in[8];
    float* out = (float*)d_out;

    const size_t XS   = (size_t)Bn * Sn * En;       // 8,388,608
    const size_t WCS  = (size_t)3 * En * Hn * Dn;   // 3,145,728
    const size_t WOS  = (size_t)En * En;            // 1,048,576
    const size_t QSZ  = (size_t)Bn * Hn * Sn * Dn;  // 8,388,608

    short* Ax    = (short*)d_ws;
    short* Wcat  = Ax + XS;
    short* Wob   = Wcat + WCS;
    float* biasc = (float*)(Wob + WOS);
    short* Qb    = (short*)(biasc + 3072);
    short* Kb    = Qb + QSZ;
    short* Vtb   = Kb + QSZ;
    short* Cbf   = Vtb + QSZ;

    conv_x_kernel<<<dim3(XS / (256 * 4)), 256, 0, stream>>>(x, Ax);
    build_wcat_kernel<<<dim3(3072), 256, 0, stream>>>(Wq, bq, Wk, bk, Wv, bv,
                                                      Wcat, biasc);
    conv_wo_kernel<<<dim3(En), 256, 0, stream>>>(Wo, Wob);

    // QKV: [8192 x 1024] @ [1024 x 3072]
    gemm_bt_kernel<<<dim3((Bn * Sn) / 128, 3072 / 128), 256, 0, stream>>>(
        Ax, Wcat, biasc, nullptr, Qb, Kb, Vtb, 1);

    attn_mfma_kernel<<<dim3(Sn / 128, Bn * Hn), 256, 0, stream>>>(Qb, Kb, Vtb, Cbf);

    // out: [8192 x 1024] @ Wo^T + bo
    gemm_bt_kernel<<<dim3((Bn * Sn) / 128, En / 128), 256, 0, stream>>>(
        Cbf, Wob, bo, out, nullptr, nullptr, nullptr, 0);
}

// Round 6
// 283.784 us; speedup vs baseline: 1.6661x; 1.6661x over previous
//
#include <hip/hip_runtime.h>
#include <math.h>

// B=4, S=2048, E=1024, H=16, D=64
constexpr int Bn = 4;
constexpr int Sn = 2048;
constexpr int En = 1024;
constexpr int Hn = 16;
constexpr int Dn = 64;

typedef float f32x4 __attribute__((ext_vector_type(4)));
typedef short s16x8 __attribute__((ext_vector_type(8)));
typedef short s16x4 __attribute__((ext_vector_type(4)));

__device__ __forceinline__ short f2bf(float f) {
    unsigned u = __builtin_bit_cast(unsigned, f);
    unsigned r = (u + 0x7fffu + ((u >> 16) & 1u)) >> 16;
    return (short)r;
}

// async global->LDS, 16B per lane; LDS dest = wave-uniform base + lane*16
__device__ __forceinline__ void glds16(const short* g, short* l) {
    __builtin_amdgcn_global_load_lds(
        (const __attribute__((address_space(1))) short*)g,
        (__attribute__((address_space(3))) short*)l, 16, 0, 0);
}

// ---------------------------------------------------------------------------
// Conversion kernels
// ---------------------------------------------------------------------------
__global__ __launch_bounds__(256) void conv_x_kernel(
    const float* __restrict__ x, short* __restrict__ y)
{
    size_t i = ((size_t)blockIdx.x * 256 + threadIdx.x) * 4;
    float4 v = *(const float4*)(x + i);
    s16x4 o;
    o[0] = f2bf(v.x); o[1] = f2bf(v.y); o[2] = f2bf(v.z); o[3] = f2bf(v.w);
    *(s16x4*)(y + i) = o;
}

// Wcat[n][e] bf16, n = p*1024 + h*64 + d. Coalesced LDS-transpose version.
__global__ __launch_bounds__(256) void build_wcat_kernel(
    const float* __restrict__ Wq, const float* __restrict__ bq,
    const float* __restrict__ Wk, const float* __restrict__ bk,
    const float* __restrict__ Wv, const float* __restrict__ bv,
    short* __restrict__ Wcat, float* __restrict__ bias_cat)
{
    const int et = blockIdx.x, h = blockIdx.y, p = blockIdx.z;
    const float* W  = (p == 0) ? Wq : (p == 1) ? Wk : Wv;
    const float* bb = (p == 0) ? bq : (p == 1) ? bk : bv;
    const float* Wh = W + (size_t)h * En * Dn;

    __shared__ float T[64][65];
    const int tid = threadIdx.x;
    #pragma unroll
    for (int it = 0; it < 16; it++) {
        int idx = tid + it * 256;
        int e = idx >> 6, d = idx & 63;
        T[d][e] = Wh[(size_t)(et * 64 + e) * Dn + d];
    }
    __syncthreads();
    #pragma unroll
    for (int it = 0; it < 16; it++) {
        int idx = tid + it * 256;
        int d = idx >> 6, e = idx & 63;
        Wcat[(size_t)(p * 1024 + h * 64 + d) * En + et * 64 + e] = f2bf(T[d][e]);
    }
    if (et == 0 && tid < 64)
        bias_cat[p * 1024 + h * 64 + tid] = bb[h * 64 + tid];
}

__global__ __launch_bounds__(256) void conv_wo_kernel(
    const float* __restrict__ Wo, short* __restrict__ Wob)
{
    const size_t base = (size_t)blockIdx.x * En;
    #pragma unroll
    for (int i = 0; i < 4; i++) {
        int k = threadIdx.x + i * 256;
        Wob[base + k] = f2bf(Wo[base + k]);
    }
}

// ---------------------------------------------------------------------------
// bf16 MFMA GEMM: C[M x N] = A[M x 1024] @ Bt[N x 1024]^T (+ bias)
// 128x128 tile, BK=64, global_load_lds staging, XOR-swizzled LDS.
// mode 0: fp32 out + bias. mode 1: QKV epilogue (Q scaled by 1/8).
// ---------------------------------------------------------------------------
__global__ __launch_bounds__(256) void gemm_bt_kernel(
    const short* __restrict__ A,
    const short* __restrict__ Bt,
    const float* __restrict__ bias,
    float* __restrict__ outF,
    short* __restrict__ Qb, short* __restrict__ Kb, short* __restrict__ Vtb,
    int mode)
{
    constexpr int K = En;
    const int m0 = blockIdx.x * 128;
    const int n0 = blockIdx.y * 128;

    __shared__ short As[128 * 64];
    __shared__ short Bs[128 * 64];

    const int tid  = threadIdx.x;
    const int w    = tid >> 6;
    const int lane = tid & 63;
    const int quad = lane >> 4;
    const int l15  = lane & 15;
    const int wr = (w >> 1) * 64;
    const int wc = (w & 1) * 64;

    f32x4 acc[4][4];
    #pragma unroll
    for (int i = 0; i < 4; i++)
        #pragma unroll
        for (int j = 0; j < 4; j++)
            #pragma unroll
            for (int e = 0; e < 4; e++) acc[i][j][e] = 0.f;

    for (int k0 = 0; k0 < K; k0 += 64) {
        #pragma unroll
        for (int r = 0; r < 4; r++) {
            int c   = (r * 4 + w) * 64 + lane;
            int row = c >> 3;
            int lp  = (c & 7) ^ (row & 7);
            glds16(A + (size_t)(m0 + row) * K + k0 + lp * 8,
                   As + (r * 4 + w) * 512);
            glds16(Bt + (size_t)(n0 + row) * K + k0 + lp * 8,
                   Bs + (r * 4 + w) * 512);
        }
        __syncthreads();

        #pragma unroll
        for (int ks = 0; ks < 2; ks++) {
            s16x8 af[4], bfr[4];
            #pragma unroll
            for (int mt = 0; mt < 4; mt++) {
                int row = wr + mt * 16 + l15;
                af[mt] = *(const s16x8*)&As[row * 64 + (((ks * 4 + quad) ^ (l15 & 7)) * 8)];
            }
            #pragma unroll
            for (int nt = 0; nt < 4; nt++) {
                int row = wc + nt * 16 + l15;
                bfr[nt] = *(const s16x8*)&Bs[row * 64 + (((ks * 4 + quad) ^ (l15 & 7)) * 8)];
            }
            #pragma unroll
            for (int mt = 0; mt < 4; mt++)
                #pragma unroll
                for (int nt = 0; nt < 4; nt++)
                    acc[mt][nt] = __builtin_amdgcn_mfma_f32_16x16x32_bf16(
                        af[mt], bfr[nt], acc[mt][nt], 0, 0, 0);
        }
        __syncthreads();
    }

    if (mode == 0) {
        #pragma unroll
        for (int mt = 0; mt < 4; mt++) {
            #pragma unroll
            for (int reg = 0; reg < 4; reg++) {
                int m = m0 + wr + mt * 16 + quad * 4 + reg;
                #pragma unroll
                for (int nt = 0; nt < 4; nt++) {
                    int n = n0 + wc + nt * 16 + l15;
                    outF[(size_t)m * En + n] = acc[mt][nt][reg] + bias[n];
                }
            }
        }
    } else {
        const int p = (n0 + wc) >> 10;   // uniform over 64-wide wave tile
        const float qs = (p == 0) ? 0.125f : 1.0f;   // fold 1/sqrt(D) into Q
        #pragma unroll
        for (int mt = 0; mt < 4; mt++) {
            #pragma unroll
            for (int reg = 0; reg < 4; reg++) {
                int m = m0 + wr + mt * 16 + quad * 4 + reg;
                int b = m >> 11, s = m & 2047;
                #pragma unroll
                for (int nt = 0; nt < 4; nt++) {
                    int n = n0 + wc + nt * 16 + l15;
                    int h = (n >> 6) & 15, d = n & 63;
                    short v = f2bf((acc[mt][nt][reg] + bias[n]) * qs);
                    if (p == 0)
                        Qb[(((size_t)(b * Hn + h)) * Sn + s) * Dn + d] = v;
                    else if (p == 1)
                        Kb[(((size_t)(b * Hn + h)) * Sn + s) * Dn + d] = v;
                    else
                        Vtb[(((size_t)(b * Hn + h)) * Dn + d) * Sn + s] = v;
                }
            }
        }
    }
}

// ---------------------------------------------------------------------------
// Flash attention, bf16 MFMA, static-max softmax, balanced causal pairing.
// Block handles q-tiles {i, 31-i} (64 rows each) -> uniform 33 frag-iters.
// S^T computed via swapped MFMA so P hits LDS as 8-byte stores.
// ---------------------------------------------------------------------------
__global__ __launch_bounds__(256) void attn_mfma_kernel(
    const short* __restrict__ Q, const short* __restrict__ K,
    const short* __restrict__ Vt, short* __restrict__ Cb)
{
    constexpr int PP = 72;                  // Ps pitch in shorts
    const int i  = blockIdx.x;              // 0..15
    const int bh = blockIdx.y;              // 0..63
    const int b = bh >> 4, h = bh & 15;
    const int t0 = i, t1 = 31 - i;          // frag q-tile indices

    __shared__ short Ks[64 * 64];           // [kv][d], swizzled
    __shared__ short Vts[64 * 64];          // [d][kv], swizzled
    __shared__ short Ps[128 * PP];          // [f*64 + q][kv]
    __shared__ float l_sh[128];

    const int tid  = threadIdx.x;
    const int w    = tid >> 6;
    const int lane = tid & 63;
    const int quad = lane >> 4;
    const int l15  = lane & 15;

    const short* Kp = K + (size_t)bh * Sn * Dn;
    const short* Vp = Vt + (size_t)bh * Dn * Sn;

    const int tf[2] = {t0, t1};
    s16x8 aq[2][2];
    #pragma unroll
    for (int f = 0; f < 2; f++)
        #pragma unroll
        for (int ks = 0; ks < 2; ks++)
            aq[f][ks] = *(const s16x8*)(
                Q + ((size_t)bh * Sn + tf[f] * 64 + w * 16 + l15) * Dn +
                ks * 32 + quad * 8);

    f32x4 acc[2][4];
    #pragma unroll
    for (int f = 0; f < 2; f++)
        #pragma unroll
        for (int nt = 0; nt < 4; nt++)
            #pragma unroll
            for (int e = 0; e < 4; e++) acc[f][nt][e] = 0.f;
    float lpart[2] = {0.f, 0.f};

    for (int kt = 0; kt <= t1; kt++) {
        // stage K/Vt tiles (swizzled)
        #pragma unroll
        for (int r = 0; r < 2; r++) {
            int c   = (r * 4 + w) * 64 + lane;
            int row = c >> 3;
            int lp  = (c & 7) ^ (row & 7);
            glds16(Kp + (size_t)(kt * 64 + row) * Dn + lp * 8,
                   Ks + (r * 4 + w) * 512);
            glds16(Vp + (size_t)row * Sn + kt * 64 + lp * 8,
                   Vts + (r * 4 + w) * 512);
        }
        __syncthreads();

        // per frag: St = K @ Q^T, exp, pack, write P
        #pragma unroll
        for (int f = 0; f < 2; f++) {
            if (kt > tf[f]) continue;
            f32x4 st[4];
            #pragma unroll
            for (int nt = 0; nt < 4; nt++)
                #pragma unroll
                for (int e = 0; e < 4; e++) st[nt][e] = 0.f;
            #pragma unroll
            for (int ks = 0; ks < 2; ks++) {
                #pragma unroll
                for (int nt = 0; nt < 4; nt++) {
                    s16x8 bk = *(const s16x8*)&Ks[(nt * 16 + l15) * 64 +
                                                  (((ks * 4 + quad) ^ (l15 & 7)) * 8)];
                    st[nt] = __builtin_amdgcn_mfma_f32_16x16x32_bf16(
                        bk, aq[f][ks], st[nt], 0, 0, 0);
                }
            }
            // St rows kv = nt*16+quad*4+reg, col q = w*16+l15 (local)
            const bool diag = (kt == tf[f]);
            #pragma unroll
            for (int nt = 0; nt < 4; nt++) {
                unsigned tb[4];
                #pragma unroll
                for (int reg = 0; reg < 4; reg++) {
                    float v = __expf(st[nt][reg]);
                    if (diag && (nt * 16 + quad * 4 + reg) > (w * 16 + l15))
                        v = 0.f;
                    // truncate to bf16 (keep top 16 bits); sum the truncated
                    // value so numerator (P) and denominator (l) agree.
                    unsigned tv = __builtin_bit_cast(unsigned, v) & 0xFFFF0000u;
                    tb[reg] = tv;
                    lpart[f] += __builtin_bit_cast(float, tv);
                }
                uint2 pk;
                pk.x = (tb[0] >> 16) | tb[1];
                pk.y = (tb[2] >> 16) | tb[3];
                *(uint2*)&Ps[(f * 64 + w * 16 + l15) * PP + nt * 16 + quad * 4] = pk;
            }
        }

        // PV: O += P @ V
        #pragma unroll
        for (int ks = 0; ks < 2; ks++) {
            s16x8 bv[4];
            #pragma unroll
            for (int nt = 0; nt < 4; nt++)
                bv[nt] = *(const s16x8*)&Vts[(nt * 16 + l15) * 64 +
                                             (((ks * 4 + quad) ^ (l15 & 7)) * 8)];
            #pragma unroll
            for (int f = 0; f < 2; f++) {
                if (kt > tf[f]) continue;
                s16x8 ap = *(const s16x8*)&Ps[(f * 64 + w * 16 + l15) * PP +
                                              ks * 32 + quad * 8];
                #pragma unroll
                for (int nt = 0; nt < 4; nt++)
                    acc[f][nt] = __builtin_amdgcn_mfma_f32_16x16x32_bf16(
                        ap, bv[nt], acc[f][nt], 0, 0, 0);
            }
        }
        __syncthreads();
    }

    // finalize l (reduce across the 4 lanes sharing l15) and publish per-row
    #pragma unroll
    for (int f = 0; f < 2; f++) {
        float l = lpart[f];
        l += __shfl_xor(l, 16);
        l += __shfl_xor(l, 32);
        if (quad == 0) l_sh[f * 64 + w * 16 + l15] = l;
    }
    __syncthreads();

    // epilogue: conc[b][s][h*64+d] bf16
    #pragma unroll
    for (int f = 0; f < 2; f++) {
        #pragma unroll
        for (int reg = 0; reg < 4; reg++) {
            int s = tf[f] * 64 + w * 16 + quad * 4 + reg;
            float inv = 1.f / l_sh[f * 64 + w * 16 + quad * 4 + reg];
            #pragma unroll
            for (int nt = 0; nt < 4; nt++) {
                int d = nt * 16 + l15;
                Cb[((size_t)(b * Sn + s)) * En + h * Dn + d] =
                    f2bf(acc[f][nt][reg] * inv);
            }
        }
    }
}

// ---------------------------------------------------------------------------
extern "C" void kernel_launch(void* const* d_in, const int* in_sizes, int n_in,
                              void* d_out, int out_size, void* d_ws, size_t ws_size,
                              hipStream_t stream) {
    const float* x  = (const float*)d_in[0];
    const float* Wq = (const float*)d_in[1];
    const float* bq = (const float*)d_in[2];
    const float* Wk = (const float*)d_in[3];
    const float* bk = (const float*)d_in[4];
    const float* Wv = (const float*)d_in[5];
    const float* bv = (const float*)d_in[6];
    const float* Wo = (const float*)d_in[7];
    const float* bo = (const float*)d_in[8];
    float* out = (float*)d_out;

    const size_t XS   = (size_t)Bn * Sn * En;       // 8,388,608
    const size_t WCS  = (size_t)3 * En * Hn * Dn;   // 3,145,728
    const size_t WOS  = (size_t)En * En;            // 1,048,576
    const size_t QSZ  = (size_t)Bn * Hn * Sn * Dn;  // 8,388,608

    short* Ax    = (short*)d_ws;
    short* Wcat  = Ax + XS;
    short* Wob   = Wcat + WCS;
    float* biasc = (float*)(Wob + WOS);
    short* Qb    = (short*)(biasc + 3072);
    short* Kb    = Qb + QSZ;
    short* Vtb   = Kb + QSZ;
    short* Cbf   = Vtb + QSZ;

    conv_x_kernel<<<dim3(XS / (256 * 4)), 256, 0, stream>>>(x, Ax);
    build_wcat_kernel<<<dim3(16, 16, 3), 256, 0, stream>>>(Wq, bq, Wk, bk, Wv, bv,
                                                           Wcat, biasc);
    conv_wo_kernel<<<dim3(En), 256, 0, stream>>>(Wo, Wob);

    // QKV: [8192 x 1024] @ [1024 x 3072]
    gemm_bt_kernel<<<dim3((Bn * Sn) / 128, 3072 / 128), 256, 0, stream>>>(
        Ax, Wcat, biasc, nullptr, Qb, Kb, Vtb, 1);

    attn_mfma_kernel<<<dim3(16, Bn * Hn), 256, 0, stream>>>(Qb, Kb, Vtb, Cbf);

    // out: [8192 x 1024] @ Wo^T + bo
    gemm_bt_kernel<<<dim3((Bn * Sn) / 128, En / 128), 256, 0, stream>>>(
        Cbf, Wob, bo, out, nullptr, nullptr, nullptr, 0);
}

// Round 7
// 260.412 us; speedup vs baseline: 1.8156x; 1.0897x over previous
//
#include <hip/hip_runtime.h>
#include <math.h>

// B=4, S=2048, E=1024, H=16, D=64
constexpr int Bn = 4;
constexpr int Sn = 2048;
constexpr int En = 1024;
constexpr int Hn = 16;
constexpr int Dn = 64;

typedef float f32x4 __attribute__((ext_vector_type(4)));
typedef short s16x8 __attribute__((ext_vector_type(8)));
typedef short s16x4 __attribute__((ext_vector_type(4)));

__device__ __forceinline__ short f2bf(float f) {
    unsigned u = __builtin_bit_cast(unsigned, f);
    unsigned r = (u + 0x7fffu + ((u >> 16) & 1u)) >> 16;
    return (short)r;
}

// async global->LDS, 16B per lane; LDS dest = wave-uniform base + lane*16
__device__ __forceinline__ void glds16(const short* g, short* l) {
    __builtin_amdgcn_global_load_lds(
        (const __attribute__((address_space(1))) short*)g,
        (__attribute__((address_space(3))) short*)l, 16, 0, 0);
}

// ---------------------------------------------------------------------------
// Conversion kernels
// ---------------------------------------------------------------------------
__global__ __launch_bounds__(256) void conv_x_kernel(
    const float* __restrict__ x, short* __restrict__ y)
{
    size_t i = ((size_t)blockIdx.x * 256 + threadIdx.x) * 4;
    float4 v = *(const float4*)(x + i);
    s16x4 o;
    o[0] = f2bf(v.x); o[1] = f2bf(v.y); o[2] = f2bf(v.z); o[3] = f2bf(v.w);
    *(s16x4*)(y + i) = o;
}

// Wcat[n][e] bf16, n = p*1024 + h*64 + d. Coalesced LDS-transpose version.
__global__ __launch_bounds__(256) void build_wcat_kernel(
    const float* __restrict__ Wq, const float* __restrict__ bq,
    const float* __restrict__ Wk, const float* __restrict__ bk,
    const float* __restrict__ Wv, const float* __restrict__ bv,
    short* __restrict__ Wcat, float* __restrict__ bias_cat)
{
    const int et = blockIdx.x, h = blockIdx.y, p = blockIdx.z;
    const float* W  = (p == 0) ? Wq : (p == 1) ? Wk : Wv;
    const float* bb = (p == 0) ? bq : (p == 1) ? bk : bv;
    const float* Wh = W + (size_t)h * En * Dn;

    __shared__ float T[64][65];
    const int tid = threadIdx.x;
    #pragma unroll
    for (int it = 0; it < 16; it++) {
        int idx = tid + it * 256;
        int e = idx >> 6, d = idx & 63;
        T[d][e] = Wh[(size_t)(et * 64 + e) * Dn + d];
    }
    __syncthreads();
    #pragma unroll
    for (int it = 0; it < 16; it++) {
        int idx = tid + it * 256;
        int d = idx >> 6, e = idx & 63;
        Wcat[(size_t)(p * 1024 + h * 64 + d) * En + et * 64 + e] = f2bf(T[d][e]);
    }
    if (et == 0 && tid < 64)
        bias_cat[p * 1024 + h * 64 + tid] = bb[h * 64 + tid];
}

__global__ __launch_bounds__(256) void conv_wo_kernel(
    const float* __restrict__ Wo, short* __restrict__ Wob)
{
    const size_t base = (size_t)blockIdx.x * En;
    #pragma unroll
    for (int i = 0; i < 4; i++) {
        int k = threadIdx.x + i * 256;
        Wob[base + k] = f2bf(Wo[base + k]);
    }
}

// ---------------------------------------------------------------------------
// bf16 MFMA GEMM: C[M x N] = A[M x 1024] @ Bt[N x 1024]^T (+ bias)
// 256x128 tile, 8 waves (512 thr), BK=64, global_load_lds, XOR-swizzled LDS.
// Each wave: 64x64 subtile (wr = (w>>1)*64 in M, wc = (w&1)*64 in N).
// mode 0: fp32 out + bias. mode 1: QKV epilogue (Q scaled by 1/8; V packed).
// ---------------------------------------------------------------------------
__global__ __launch_bounds__(512) void gemm_bt_kernel(
    const short* __restrict__ A,
    const short* __restrict__ Bt,
    const float* __restrict__ bias,
    float* __restrict__ outF,
    short* __restrict__ Qb, short* __restrict__ Kb, short* __restrict__ Vtb,
    int mode)
{
    constexpr int K = En;
    const int m0 = blockIdx.x * 256;
    const int n0 = blockIdx.y * 128;

    __shared__ short As[256 * 64];   // 32 KB
    __shared__ short Bs[128 * 64];   // 16 KB

    const int tid  = threadIdx.x;
    const int w    = tid >> 6;       // 0..7
    const int lane = tid & 63;
    const int quad = lane >> 4;
    const int l15  = lane & 15;
    const int wr = (w >> 1) * 64;    // 0,64,128,192
    const int wc = (w & 1) * 64;     // 0,64

    f32x4 acc[4][4];
    #pragma unroll
    for (int i = 0; i < 4; i++)
        #pragma unroll
        for (int j = 0; j < 4; j++)
            #pragma unroll
            for (int e = 0; e < 4; e++) acc[i][j][e] = 0.f;

    for (int k0 = 0; k0 < K; k0 += 64) {
        // A: 256 rows x 64 shorts = 2048 chunks; 4 wave-issues per wave
        #pragma unroll
        for (int r = 0; r < 4; r++) {
            int c   = (r * 8 + w) * 64 + lane;
            int row = c >> 3;
            int lp  = (c & 7) ^ (row & 7);
            glds16(A + (size_t)(m0 + row) * K + k0 + lp * 8,
                   As + (r * 8 + w) * 512);
        }
        // B: 128 rows = 1024 chunks; 2 wave-issues per wave
        #pragma unroll
        for (int r = 0; r < 2; r++) {
            int c   = (r * 8 + w) * 64 + lane;
            int row = c >> 3;
            int lp  = (c & 7) ^ (row & 7);
            glds16(Bt + (size_t)(n0 + row) * K + k0 + lp * 8,
                   Bs + (r * 8 + w) * 512);
        }
        __syncthreads();

        #pragma unroll
        for (int ks = 0; ks < 2; ks++) {
            s16x8 af[4], bfr[4];
            #pragma unroll
            for (int mt = 0; mt < 4; mt++) {
                int row = wr + mt * 16 + l15;
                af[mt] = *(const s16x8*)&As[row * 64 + (((ks * 4 + quad) ^ (l15 & 7)) * 8)];
            }
            #pragma unroll
            for (int nt = 0; nt < 4; nt++) {
                int row = wc + nt * 16 + l15;
                bfr[nt] = *(const s16x8*)&Bs[row * 64 + (((ks * 4 + quad) ^ (l15 & 7)) * 8)];
            }
            #pragma unroll
            for (int mt = 0; mt < 4; mt++)
                #pragma unroll
                for (int nt = 0; nt < 4; nt++)
                    acc[mt][nt] = __builtin_amdgcn_mfma_f32_16x16x32_bf16(
                        af[mt], bfr[nt], acc[mt][nt], 0, 0, 0);
        }
        __syncthreads();
    }

    if (mode == 0) {
        #pragma unroll
        for (int mt = 0; mt < 4; mt++) {
            #pragma unroll
            for (int reg = 0; reg < 4; reg++) {
                int m = m0 + wr + mt * 16 + quad * 4 + reg;
                #pragma unroll
                for (int nt = 0; nt < 4; nt++) {
                    int n = n0 + wc + nt * 16 + l15;
                    outF[(size_t)m * En + n] = acc[mt][nt][reg] + bias[n];
                }
            }
        }
    } else {
        const int p = (n0 + wc) >> 10;   // uniform over 64-wide wave tile
        if (p < 2) {
            const float qs = (p == 0) ? 0.125f : 1.0f;  // fold 1/sqrt(D) into Q
            short* dst = (p == 0) ? Qb : Kb;
            #pragma unroll
            for (int mt = 0; mt < 4; mt++) {
                #pragma unroll
                for (int reg = 0; reg < 4; reg++) {
                    int m = m0 + wr + mt * 16 + quad * 4 + reg;
                    int b = m >> 11, s = m & 2047;
                    #pragma unroll
                    for (int nt = 0; nt < 4; nt++) {
                        int n = n0 + wc + nt * 16 + l15;
                        int h = (n >> 6) & 15, d = n & 63;
                        dst[(((size_t)(b * Hn + h)) * Sn + s) * Dn + d] =
                            f2bf((acc[mt][nt][reg] + bias[n]) * qs);
                    }
                }
            }
        } else {
            // V: regs 0..3 are contiguous in s -> one 8B store per (mt,nt)
            #pragma unroll
            for (int mt = 0; mt < 4; mt++) {
                int m = m0 + wr + mt * 16 + quad * 4;   // reg 0; same b for all 4
                int b = m >> 11, s = m & 2047;
                #pragma unroll
                for (int nt = 0; nt < 4; nt++) {
                    int n = n0 + wc + nt * 16 + l15;
                    int h = (n >> 6) & 15, d = n & 63;
                    s16x4 pk;
                    #pragma unroll
                    for (int reg = 0; reg < 4; reg++)
                        pk[reg] = f2bf(acc[mt][nt][reg] + bias[n]);
                    *(s16x4*)(Vtb + (((size_t)(b * Hn + h)) * Dn + d) * Sn + s) = pk;
                }
            }
        }
    }
}

// ---------------------------------------------------------------------------
// Flash attention, bf16 MFMA, static-max softmax, balanced causal pairing.
// Block handles q-tiles {i, 31-i} (64 rows each) -> uniform 33 frag-iters.
// S^T computed via swapped MFMA so P hits LDS as 8-byte stores.
// ---------------------------------------------------------------------------
__global__ __launch_bounds__(256) void attn_mfma_kernel(
    const short* __restrict__ Q, const short* __restrict__ K,
    const short* __restrict__ Vt, short* __restrict__ Cb)
{
    constexpr int PP = 72;                  // Ps pitch in shorts
    const int i  = blockIdx.x;              // 0..15
    const int bh = blockIdx.y;              // 0..63
    const int b = bh >> 4, h = bh & 15;
    const int t0 = i, t1 = 31 - i;          // frag q-tile indices

    __shared__ short Ks[64 * 64];           // [kv][d], swizzled
    __shared__ short Vts[64 * 64];          // [d][kv], swizzled
    __shared__ short Ps[128 * PP];          // [f*64 + q][kv]
    __shared__ float l_sh[128];

    const int tid  = threadIdx.x;
    const int w    = tid >> 6;
    const int lane = tid & 63;
    const int quad = lane >> 4;
    const int l15  = lane & 15;

    const short* Kp = K + (size_t)bh * Sn * Dn;
    const short* Vp = Vt + (size_t)bh * Dn * Sn;

    const int tf[2] = {t0, t1};
    s16x8 aq[2][2];
    #pragma unroll
    for (int f = 0; f < 2; f++)
        #pragma unroll
        for (int ks = 0; ks < 2; ks++)
            aq[f][ks] = *(const s16x8*)(
                Q + ((size_t)bh * Sn + tf[f] * 64 + w * 16 + l15) * Dn +
                ks * 32 + quad * 8);

    f32x4 acc[2][4];
    #pragma unroll
    for (int f = 0; f < 2; f++)
        #pragma unroll
        for (int nt = 0; nt < 4; nt++)
            #pragma unroll
            for (int e = 0; e < 4; e++) acc[f][nt][e] = 0.f;
    float lpart[2] = {0.f, 0.f};

    for (int kt = 0; kt <= t1; kt++) {
        // stage K/Vt tiles (swizzled)
        #pragma unroll
        for (int r = 0; r < 2; r++) {
            int c   = (r * 4 + w) * 64 + lane;
            int row = c >> 3;
            int lp  = (c & 7) ^ (row & 7);
            glds16(Kp + (size_t)(kt * 64 + row) * Dn + lp * 8,
                   Ks + (r * 4 + w) * 512);
            glds16(Vp + (size_t)row * Sn + kt * 64 + lp * 8,
                   Vts + (r * 4 + w) * 512);
        }
        __syncthreads();

        // per frag: St = K @ Q^T, exp, pack, write P
        #pragma unroll
        for (int f = 0; f < 2; f++) {
            if (kt > tf[f]) continue;
            f32x4 st[4];
            #pragma unroll
            for (int nt = 0; nt < 4; nt++)
                #pragma unroll
                for (int e = 0; e < 4; e++) st[nt][e] = 0.f;
            #pragma unroll
            for (int ks = 0; ks < 2; ks++) {
                #pragma unroll
                for (int nt = 0; nt < 4; nt++) {
                    s16x8 bk = *(const s16x8*)&Ks[(nt * 16 + l15) * 64 +
                                                  (((ks * 4 + quad) ^ (l15 & 7)) * 8)];
                    st[nt] = __builtin_amdgcn_mfma_f32_16x16x32_bf16(
                        bk, aq[f][ks], st[nt], 0, 0, 0);
                }
            }
            // St rows kv = nt*16+quad*4+reg, col q = w*16+l15 (local)
            const bool diag = (kt == tf[f]);
            #pragma unroll
            for (int nt = 0; nt < 4; nt++) {
                unsigned tb[4];
                #pragma unroll
                for (int reg = 0; reg < 4; reg++) {
                    float v = __expf(st[nt][reg]);
                    if (diag && (nt * 16 + quad * 4 + reg) > (w * 16 + l15))
                        v = 0.f;
                    unsigned tv = __builtin_bit_cast(unsigned, v) & 0xFFFF0000u;
                    tb[reg] = tv;
                    lpart[f] += __builtin_bit_cast(float, tv);
                }
                uint2 pk;
                pk.x = (tb[0] >> 16) | tb[1];
                pk.y = (tb[2] >> 16) | tb[3];
                *(uint2*)&Ps[(f * 64 + w * 16 + l15) * PP + nt * 16 + quad * 4] = pk;
            }
        }

        // PV: O += P @ V
        #pragma unroll
        for (int ks = 0; ks < 2; ks++) {
            s16x8 bv[4];
            #pragma unroll
            for (int nt = 0; nt < 4; nt++)
                bv[nt] = *(const s16x8*)&Vts[(nt * 16 + l15) * 64 +
                                             (((ks * 4 + quad) ^ (l15 & 7)) * 8)];
            #pragma unroll
            for (int f = 0; f < 2; f++) {
                if (kt > tf[f]) continue;
                s16x8 ap = *(const s16x8*)&Ps[(f * 64 + w * 16 + l15) * PP +
                                              ks * 32 + quad * 8];
                #pragma unroll
                for (int nt = 0; nt < 4; nt++)
                    acc[f][nt] = __builtin_amdgcn_mfma_f32_16x16x32_bf16(
                        ap, bv[nt], acc[f][nt], 0, 0, 0);
            }
        }
        __syncthreads();
    }

    // finalize l and publish per-row
    #pragma unroll
    for (int f = 0; f < 2; f++) {
        float l = lpart[f];
        l += __shfl_xor(l, 16);
        l += __shfl_xor(l, 32);
        if (quad == 0) l_sh[f * 64 + w * 16 + l15] = l;
    }
    __syncthreads();

    // epilogue: conc[b][s][h*64+d] bf16
    #pragma unroll
    for (int f = 0; f < 2; f++) {
        #pragma unroll
        for (int reg = 0; reg < 4; reg++) {
            int s = tf[f] * 64 + w * 16 + quad * 4 + reg;
            float inv = 1.f / l_sh[f * 64 + w * 16 + quad * 4 + reg];
            #pragma unroll
            for (int nt = 0; nt < 4; nt++) {
                int d = nt * 16 + l15;
                Cb[((size_t)(b * Sn + s)) * En + h * Dn + d] =
                    f2bf(acc[f][nt][reg] * inv);
            }
        }
    }
}

// ---------------------------------------------------------------------------
extern "C" void kernel_launch(void* const* d_in, const int* in_sizes, int n_in,
                              void* d_out, int out_size, void* d_ws, size_t ws_size,
                              hipStream_t stream) {
    const float* x  = (const float*)d_in[0];
    const float* Wq = (const float*)d_in[1];
    const float* bq = (const float*)d_in[2];
    const float* Wk = (const float*)d_in[3];
    const float* bk = (const float*)d_in[4];
    const float* Wv = (const float*)d_in[5];
    const float* bv = (const float*)d_in[6];
    const float* Wo = (const float*)d_in[7];
    const float* bo = (const float*)d_in[8];
    float* out = (float*)d_out;

    const size_t XS   = (size_t)Bn * Sn * En;       // 8,388,608
    const size_t WCS  = (size_t)3 * En * Hn * Dn;   // 3,145,728
    const size_t WOS  = (size_t)En * En;            // 1,048,576
    const size_t QSZ  = (size_t)Bn * Hn * Sn * Dn;  // 8,388,608

    short* Ax    = (short*)d_ws;
    short* Wcat  = Ax + XS;
    short* Wob   = Wcat + WCS;
    float* biasc = (float*)(Wob + WOS);
    short* Qb    = (short*)(biasc + 3072);
    short* Kb    = Qb + QSZ;
    short* Vtb   = Kb + QSZ;
    short* Cbf   = Vtb + QSZ;

    conv_x_kernel<<<dim3(XS / (256 * 4)), 256, 0, stream>>>(x, Ax);
    build_wcat_kernel<<<dim3(16, 16, 3), 256, 0, stream>>>(Wq, bq, Wk, bk, Wv, bv,
                                                           Wcat, biasc);
    conv_wo_kernel<<<dim3(En), 256, 0, stream>>>(Wo, Wob);

    // QKV: [8192 x 1024] @ [1024 x 3072]
    gemm_bt_kernel<<<dim3((Bn * Sn) / 256, 3072 / 128), 512, 0, stream>>>(
        Ax, Wcat, biasc, nullptr, Qb, Kb, Vtb, 1);

    attn_mfma_kernel<<<dim3(16, Bn * Hn), 256, 0, stream>>>(Qb, Kb, Vtb, Cbf);

    // out: [8192 x 1024] @ Wo^T + bo
    gemm_bt_kernel<<<dim3((Bn * Sn) / 256, En / 128), 512, 0, stream>>>(
        Cbf, Wob, bo, out, nullptr, nullptr, nullptr, 0);
}